// Round 2
// baseline (169.124 us; speedup 1.0000x reference)
//
#include <hip/hip_runtime.h>

#define BB 4
#define NN 2048
#define DD 4
#define QQ (NN / 4)          // 512 quads along j
#define BLOCK 256
#define JIT (QQ / 64)        // 8 j-iterations per lane

typedef float f4 __attribute__((ext_vector_type(4)));
typedef _Float16 h8 __attribute__((ext_vector_type(8)));
typedef _Float16 h2 __attribute__((ext_vector_type(2)));

#if __has_builtin(__builtin_amdgcn_fdot2) && __has_builtin(__builtin_amdgcn_cvt_pkrtz)
#define USE_FDOT2 1
#endif

// ---------------- precompute: sincos(theta) -> fp32 arrays (epilogue) + fp16 quad-packed (main loop)
// scT layout: [b][d][q] -> 8 halves {s(j0),c(j0),s(j1),c(j1),s(j2),c(j2),s(j3),c(j3)}, j=4q+u
// NOTE: each 32-bit word of an scT element is an (s,c) fp16 pair == a v_dot2_f32_f16 operand.
__global__ __launch_bounds__(BLOCK) void precomp(const float* __restrict__ theta,
                                                 float* __restrict__ sArr,
                                                 float* __restrict__ cArr,
                                                 h8* __restrict__ scT) {
    const int t = blockIdx.x * BLOCK + threadIdx.x;     // [0, B*QQ) = 2048
    const int b = t / QQ, q = t % QQ;
    const f4* theta4 = (const f4*)theta;
    f4* s4 = (f4*)sArr;
    f4* c4 = (f4*)cArr;

    float s[4][4], c[4][4];                              // [u][d]
    #pragma unroll
    for (int u = 0; u < 4; ++u) {
        const f4 th = theta4[(size_t)b * NN + 4 * q + u];
        #pragma unroll
        for (int d = 0; d < 4; ++d) __sincosf(th[d], &s[u][d], &c[u][d]);
    }
    #pragma unroll
    for (int u = 0; u < 4; ++u) {
        f4 sv, cv;
        #pragma unroll
        for (int d = 0; d < 4; ++d) { sv[d] = s[u][d]; cv[d] = c[u][d]; }
        s4[(size_t)b * NN + 4 * q + u] = sv;
        c4[(size_t)b * NN + 4 * q + u] = cv;
    }
    #pragma unroll
    for (int d = 0; d < 4; ++d) {
        h8 w;
        #pragma unroll
        for (int u = 0; u < 4; ++u) {
            w[2 * u]     = (_Float16)s[u][d];
            w[2 * u + 1] = (_Float16)c[u][d];
        }
        scT[((size_t)b * 4 + d) * QQ + q] = w;
    }
}

// ---------------- main: 2048 blocks, 4 waves/block, ONE row per wave, sc in LDS
__global__ __launch_bounds__(BLOCK, 5) void kuramoto_main(
    const float* __restrict__ theta,
    const float* __restrict__ gam,
    const float* __restrict__ aff,
    const float* __restrict__ alp,
    const float* __restrict__ omega,
    const float* __restrict__ kappa,
    const float* __restrict__ bias,
    const float* __restrict__ sArr,
    const float* __restrict__ cArr,
    const uint4* __restrict__ scT,
    float* __restrict__ out)
{
    // XCD swizzle: batch-siblings (same rows, b=0..3) within a 32-block window
    // land on the same XCD close in time -> bias L2 reuse.
    const int x   = blockIdx.x;                          // [0, 2048)
    const int low = x & 31;
    const int b   = low >> 3;
    const int g   = (x >> 5) * 8 + (low & 7);            // row-group [0, 512)
    const int i0  = g * 4;

    const int tid  = threadIdx.x;
    const int wave = tid >> 6;
    const int lane = tid & 63;
    const int i    = i0 + wave;                          // this wave's row

    // ---- stage this batch's sincos table into LDS (32 KB) ----
    __shared__ uint4 lsc[4 * QQ];
    {
        const uint4* gsc = scT + (size_t)b * 4 * QQ;
        #pragma unroll
        for (int k = 0; k < (4 * QQ) / BLOCK; ++k)
            lsc[tid + BLOCK * k] = gsc[tid + BLOCK * k];
    }
    __syncthreads();

    const f4* arow = (const f4*)(aff + (size_t)b * NN * NN) + (size_t)i * QQ;
    const f4* lrow = (const f4*)(alp + (size_t)b * NN * NN) + (size_t)i * QQ;
    const f4* brow = (const f4*)bias + (size_t)i * QQ;

    f4 accU = {0.f, 0.f, 0.f, 0.f};
    f4 accV = {0.f, 0.f, 0.f, 0.f};

    // depth-1 double-buffered global streams
    f4 av[2], lv[2], bv[2];
    av[0] = __builtin_nontemporal_load(&arow[lane]);
    lv[0] = __builtin_nontemporal_load(&lrow[lane]);
    bv[0] = brow[lane];

    #pragma unroll
    for (int jj = 0; jj < JIT; ++jj) {
        const int cur = jj & 1;
        const int nxt = cur ^ 1;
        const int q   = lane + 64 * jj;

        if (jj + 1 < JIT) {
            const int qn = q + 64;
            av[nxt] = __builtin_nontemporal_load(&arow[qn]);
            lv[nxt] = __builtin_nontemporal_load(&lrow[qn]);
            bv[nxt] = brow[qn];
        }

        // (s,c) fp16 pairs for this quad, one b128 per d; each 32-bit word is
        // a ready-made dot2 operand {sin(θj), cos(θj)} — no unpack needed.
        const uint4 w0 = lsc[0 * QQ + q];
        const uint4 w1 = lsc[1 * QQ + q];
        const uint4 w2 = lsc[2 * QQ + q];
        const uint4 w3 = lsc[3 * QQ + q];
        const unsigned wq[4][4] = {
            {w0.x, w0.y, w0.z, w0.w},
            {w1.x, w1.y, w1.z, w1.w},
            {w2.x, w2.y, w2.z, w2.w},
            {w3.x, w3.y, w3.z, w3.w},
        };

        const f4 alr = lv[cur] + bv[cur];
        const f4 af  = av[cur];
        #pragma unroll
        for (int u = 0; u < 4; ++u) {
            float sa, ca;
            __sincosf(alr[u], &sa, &ca);
            const float wc = af[u] * ca;
            const float ws = af[u] * sa;
#ifdef USE_FDOT2
            // accU[d] += wc*s - ws*c ; accV[d] += ws*s + wc*c
            const h2 pw = __builtin_bit_cast(h2, __builtin_amdgcn_cvt_pkrtz(wc, -ws));
            const h2 pv = __builtin_bit_cast(h2, __builtin_amdgcn_cvt_pkrtz(ws,  wc));
            #pragma unroll
            for (int d = 0; d < 4; ++d) {
                const h2 pr = __builtin_bit_cast(h2, wq[d][u]);
                accU[d] = __builtin_amdgcn_fdot2(pw, pr, accU[d], false);
                accV[d] = __builtin_amdgcn_fdot2(pv, pr, accV[d], false);
            }
#else
            #pragma unroll
            for (int d = 0; d < 4; ++d) {
                const h2 pr = __builtin_bit_cast(h2, wq[d][u]);
                const float sj = (float)pr[0];
                const float cj = (float)pr[1];
                accU[d] += wc * sj - ws * cj;
                accV[d] += wc * cj + ws * sj;
            }
#endif
        }
    }

    // ---- wave-local shuffle reduction; no barrier needed ----
    #pragma unroll
    for (int off = 32; off >= 1; off >>= 1) {
        #pragma unroll
        for (int d = 0; d < 4; ++d) {
            accU[d] += __shfl_down(accU[d], off, 64);
            accV[d] += __shfl_down(accV[d], off, 64);
        }
    }

    if (lane == 0) {
        const f4* theta4 = (const f4*)theta;
        const f4* gam4   = (const f4*)gam;
        const f4* om4    = (const f4*)omega;
        const f4* kp4    = (const f4*)kappa;
        const f4* s4     = (const f4*)sArr;
        const f4* c4     = (const f4*)cArr;
        f4* out4         = (f4*)out;

        const size_t base = (size_t)b * NN + i;
        const f4 th = theta4[base];
        const f4 gm = gam4[base];
        const f4 om = om4[i];
        const f4 kp = kp4[i];
        const f4 si = s4[base];
        const f4 ci = c4[base];
        f4 o;
        #pragma unroll
        for (int d = 0; d < 4; ++d) {
            const float coup = (1.0f / (float)NN) * (ci[d] * accU[d] - si[d] * accV[d]);
            o[d] = th[d] + om[d] + kp[d] * (gm[d] - th[d]) + coup;
        }
        out4[base] = o;
    }
}

extern "C" void kernel_launch(void* const* d_in, const int* in_sizes, int n_in,
                              void* d_out, int out_size, void* d_ws, size_t ws_size,
                              hipStream_t stream) {
    const float* theta = (const float*)d_in[0];
    const float* gam   = (const float*)d_in[1];
    const float* aff   = (const float*)d_in[2];
    const float* alp   = (const float*)d_in[3];
    const float* omega = (const float*)d_in[4];
    const float* kappa = (const float*)d_in[5];
    const float* bias  = (const float*)d_in[6];
    float* out  = (float*)d_out;

    float* sArr = (float*)d_ws;                          // [B*N*D] fp32
    float* cArr = sArr + BB * NN * DD;                   // [B*N*D] fp32
    h8*    scT  = (h8*)(cArr + BB * NN * DD);            // [B][4][QQ] fp16 pairs, 128 KB

    precomp<<<(BB * QQ) / BLOCK, BLOCK, 0, stream>>>(theta, sArr, cArr, scT);
    kuramoto_main<<<BB * (NN / 4), BLOCK, 0, stream>>>(
        theta, gam, aff, alp, omega, kappa, bias, sArr, cArr, (const uint4*)scT, out);
}

// Round 3
// 167.018 us; speedup vs baseline: 1.0126x; 1.0126x over previous
//
#include <hip/hip_runtime.h>

#define BB 4
#define NN 2048
#define DD 4
#define QQ (NN / 4)          // 512 quads along j
#define BLOCK 256
#define JIT (QQ / 64)        // 8 j-iterations per lane

typedef float f4 __attribute__((ext_vector_type(4)));
typedef _Float16 h2 __attribute__((ext_vector_type(2)));

#if __has_builtin(__builtin_amdgcn_fdot2) && __has_builtin(__builtin_amdgcn_cvt_pkrtz)
#define USE_FDOT2 1
#endif

static __device__ __forceinline__ unsigned pack_sc(float s, float c) {
#ifdef USE_FDOT2
    return __builtin_bit_cast(unsigned, __builtin_amdgcn_cvt_pkrtz(s, c));
#else
    h2 p; p[0] = (_Float16)s; p[1] = (_Float16)c;
    return __builtin_bit_cast(unsigned, p);
#endif
}

// ---------------- single fused kernel: 2048 blocks, 4 waves/block, one row per wave.
// Each block rebuilds its batch's sincos table in LDS from theta directly (no precomp
// kernel, no global scT round-trip). First global tile is issued BEFORE the table
// build so HBM latency hides under the ~400-cycle sincos phase.
__global__ __launch_bounds__(BLOCK, 5) void kuramoto_fused(
    const float* __restrict__ theta,
    const float* __restrict__ gam,
    const float* __restrict__ aff,
    const float* __restrict__ alp,
    const float* __restrict__ omega,
    const float* __restrict__ kappa,
    const float* __restrict__ bias,
    float* __restrict__ out)
{
    // XCD swizzle: batch-siblings (same rows, b=0..3) land on the same XCD
    // close in time -> bias-row L2 reuse.
    const int x   = blockIdx.x;                          // [0, 2048)
    const int low = x & 31;
    const int b   = low >> 3;
    const int g   = (x >> 5) * 8 + (low & 7);            // row-group [0, 512)
    const int i0  = g * 4;

    const int tid  = threadIdx.x;
    const int wave = tid >> 6;
    const int lane = tid & 63;
    const int i    = i0 + wave;                          // this wave's row

    const f4* arow = (const f4*)(aff + (size_t)b * NN * NN) + (size_t)i * QQ;
    const f4* lrow = (const f4*)(alp + (size_t)b * NN * NN) + (size_t)i * QQ;
    const f4* brow = (const f4*)bias + (size_t)i * QQ;

    // ---- issue first tile early: latency hides under the sincos table build ----
    f4 av[2], lv[2], bv[2];
    av[0] = __builtin_nontemporal_load(&arow[lane]);
    lv[0] = __builtin_nontemporal_load(&lrow[lane]);
    bv[0] = brow[lane];

    // ---- build this batch's sincos table in LDS (32 KB) ----
    // entry (d, q) = 4 fp16 (s,c) pairs for j = 4q..4q+3; each 32-bit word is a
    // ready-made v_dot2_f32_f16 operand {sin(θj), cos(θj)}.
    __shared__ uint4 lsc[4 * QQ];
    const f4* theta4 = (const f4*)theta + (size_t)b * NN;
    #pragma unroll
    for (int k = 0; k < QQ / BLOCK; ++k) {               // 2 quads per thread
        const int q = tid + BLOCK * k;
        float s[4][4], c[4][4];                          // [u][d]
        #pragma unroll
        for (int u = 0; u < 4; ++u) {
            const f4 th = theta4[4 * q + u];
            #pragma unroll
            for (int d = 0; d < 4; ++d) __sincosf(th[d], &s[u][d], &c[u][d]);
        }
        #pragma unroll
        for (int d = 0; d < 4; ++d) {
            uint4 w;
            w.x = pack_sc(s[0][d], c[0][d]);
            w.y = pack_sc(s[1][d], c[1][d]);
            w.z = pack_sc(s[2][d], c[2][d]);
            w.w = pack_sc(s[3][d], c[3][d]);
            lsc[d * QQ + q] = w;
        }
    }
    __syncthreads();

    f4 accU = {0.f, 0.f, 0.f, 0.f};
    f4 accV = {0.f, 0.f, 0.f, 0.f};

    #pragma unroll
    for (int jj = 0; jj < JIT; ++jj) {
        const int cur = jj & 1;
        const int nxt = cur ^ 1;
        const int q   = lane + 64 * jj;

        if (jj + 1 < JIT) {
            const int qn = q + 64;
            av[nxt] = __builtin_nontemporal_load(&arow[qn]);
            lv[nxt] = __builtin_nontemporal_load(&lrow[qn]);
            bv[nxt] = brow[qn];
        }

        // (s,c) fp16 pairs for this quad, one b128 per d.
        const uint4 w0 = lsc[0 * QQ + q];
        const uint4 w1 = lsc[1 * QQ + q];
        const uint4 w2 = lsc[2 * QQ + q];
        const uint4 w3 = lsc[3 * QQ + q];
        const unsigned wq[4][4] = {
            {w0.x, w0.y, w0.z, w0.w},
            {w1.x, w1.y, w1.z, w1.w},
            {w2.x, w2.y, w2.z, w2.w},
            {w3.x, w3.y, w3.z, w3.w},
        };

        const f4 alr = lv[cur] + bv[cur];
        const f4 af  = av[cur];
        #pragma unroll
        for (int u = 0; u < 4; ++u) {
            float sa, ca;
            __sincosf(alr[u], &sa, &ca);
            const float wc = af[u] * ca;
            const float ws = af[u] * sa;
#ifdef USE_FDOT2
            // accU[d] += wc*s - ws*c ; accV[d] += ws*s + wc*c
            const h2 pw = __builtin_bit_cast(h2, __builtin_amdgcn_cvt_pkrtz(wc, -ws));
            const h2 pv = __builtin_bit_cast(h2, __builtin_amdgcn_cvt_pkrtz(ws,  wc));
            #pragma unroll
            for (int d = 0; d < 4; ++d) {
                const h2 pr = __builtin_bit_cast(h2, wq[d][u]);
                accU[d] = __builtin_amdgcn_fdot2(pw, pr, accU[d], false);
                accV[d] = __builtin_amdgcn_fdot2(pv, pr, accV[d], false);
            }
#else
            #pragma unroll
            for (int d = 0; d < 4; ++d) {
                const h2 pr = __builtin_bit_cast(h2, wq[d][u]);
                const float sj = (float)pr[0];
                const float cj = (float)pr[1];
                accU[d] += wc * sj - ws * cj;
                accV[d] += wc * cj + ws * sj;
            }
#endif
        }
    }

    // ---- wave-local shuffle reduction; no barrier needed ----
    #pragma unroll
    for (int off = 32; off >= 1; off >>= 1) {
        #pragma unroll
        for (int d = 0; d < 4; ++d) {
            accU[d] += __shfl_down(accU[d], off, 64);
            accV[d] += __shfl_down(accV[d], off, 64);
        }
    }

    if (lane == 0) {
        const f4* gam4 = (const f4*)gam;
        const f4* om4  = (const f4*)omega;
        const f4* kp4  = (const f4*)kappa;
        f4* out4       = (f4*)out;

        const size_t base = (size_t)b * NN + i;
        const f4 th = theta4[i];                         // theta4 already offset by b*NN
        const f4 gm = gam4[base];
        const f4 om = om4[i];
        const f4 kp = kp4[i];
        f4 o;
        #pragma unroll
        for (int d = 0; d < 4; ++d) {
            float si, ci;
            __sincosf(th[d], &si, &ci);                  // fp32 epilogue sincos, inline
            const float coup = (1.0f / (float)NN) * (ci * accU[d] - si * accV[d]);
            o[d] = th[d] + om[d] + kp[d] * (gm[d] - th[d]) + coup;
        }
        out4[base] = o;
    }
}

extern "C" void kernel_launch(void* const* d_in, const int* in_sizes, int n_in,
                              void* d_out, int out_size, void* d_ws, size_t ws_size,
                              hipStream_t stream) {
    const float* theta = (const float*)d_in[0];
    const float* gam   = (const float*)d_in[1];
    const float* aff   = (const float*)d_in[2];
    const float* alp   = (const float*)d_in[3];
    const float* omega = (const float*)d_in[4];
    const float* kappa = (const float*)d_in[5];
    const float* bias  = (const float*)d_in[6];
    float* out  = (float*)d_out;
    (void)d_ws; (void)ws_size;                           // workspace no longer needed

    kuramoto_fused<<<BB * (NN / 4), BLOCK, 0, stream>>>(
        theta, gam, aff, alp, omega, kappa, bias, out);
}

// Round 4
// 166.417 us; speedup vs baseline: 1.0163x; 1.0036x over previous
//
#include <hip/hip_runtime.h>

#define BB 4
#define NN 2048
#define DD 4
#define QQ (NN / 4)          // 512 quads along j
#define BLOCK 256
#define JIT (QQ / 64)        // 8 j-iterations per lane

typedef float f4 __attribute__((ext_vector_type(4)));
typedef _Float16 h2 __attribute__((ext_vector_type(2)));

#if __has_builtin(__builtin_amdgcn_fdot2) && __has_builtin(__builtin_amdgcn_cvt_pkrtz)
#define USE_FDOT2 1
#endif

static __device__ __forceinline__ unsigned pack_sc(float s, float c) {
#ifdef USE_FDOT2
    return __builtin_bit_cast(unsigned, __builtin_amdgcn_cvt_pkrtz(s, c));
#else
    h2 p; p[0] = (_Float16)s; p[1] = (_Float16)c;
    return __builtin_bit_cast(unsigned, p);
#endif
}

// ---------------- single fused kernel: 2048 blocks, 4 waves/block, one row per wave.
// Depth-2 rotating prefetch: two tiles issued BEFORE the sincos table build, so both
// the table-build VALU phase and the first loop iteration run with HBM latency covered.
// launch_bounds (256,4): ~115 VGPR budget, no forced squeeze; LDS (32KB) caps residency.
__global__ __launch_bounds__(BLOCK, 4) void kuramoto_fused(
    const float* __restrict__ theta,
    const float* __restrict__ gam,
    const float* __restrict__ aff,
    const float* __restrict__ alp,
    const float* __restrict__ omega,
    const float* __restrict__ kappa,
    const float* __restrict__ bias,
    float* __restrict__ out)
{
    // XCD swizzle: batch-siblings (same rows, b=0..3) are 8 apart in blockIdx ->
    // same XCD (x%8) close in time -> bias-row L2 reuse.
    const int x   = blockIdx.x;                          // [0, 2048)
    const int low = x & 31;
    const int b   = low >> 3;
    const int g   = (x >> 5) * 8 + (low & 7);            // row-group [0, 512)
    const int i0  = g * 4;

    const int tid  = threadIdx.x;
    const int wave = tid >> 6;
    const int lane = tid & 63;
    const int i    = i0 + wave;                          // this wave's row

    const f4* arow = (const f4*)(aff + (size_t)b * NN * NN) + (size_t)i * QQ;
    const f4* lrow = (const f4*)(alp + (size_t)b * NN * NN) + (size_t)i * QQ;
    const f4* brow = (const f4*)bias + (size_t)i * QQ;

    // ---- issue tiles 0 and 1 early: latency hides under the sincos table build ----
    f4 av[3], lv[3], bv[3];
    av[0] = __builtin_nontemporal_load(&arow[lane]);
    lv[0] = __builtin_nontemporal_load(&lrow[lane]);
    bv[0] = brow[lane];
    av[1] = __builtin_nontemporal_load(&arow[lane + 64]);
    lv[1] = __builtin_nontemporal_load(&lrow[lane + 64]);
    bv[1] = brow[lane + 64];

    // ---- build this batch's sincos table in LDS (32 KB) ----
    // entry (d, q) = 4 fp16 (s,c) pairs for j = 4q..4q+3; each 32-bit word is a
    // ready-made v_dot2_f32_f16 operand {sin(θj), cos(θj)}.
    __shared__ uint4 lsc[4 * QQ];
    const f4* theta4 = (const f4*)theta + (size_t)b * NN;
    #pragma unroll
    for (int k = 0; k < QQ / BLOCK; ++k) {               // 2 quads per thread
        const int q = tid + BLOCK * k;
        float s[4][4], c[4][4];                          // [u][d]
        #pragma unroll
        for (int u = 0; u < 4; ++u) {
            const f4 th = theta4[4 * q + u];
            #pragma unroll
            for (int d = 0; d < 4; ++d) __sincosf(th[d], &s[u][d], &c[u][d]);
        }
        #pragma unroll
        for (int d = 0; d < 4; ++d) {
            uint4 w;
            w.x = pack_sc(s[0][d], c[0][d]);
            w.y = pack_sc(s[1][d], c[1][d]);
            w.z = pack_sc(s[2][d], c[2][d]);
            w.w = pack_sc(s[3][d], c[3][d]);
            lsc[d * QQ + q] = w;
        }
    }
    __syncthreads();

    f4 accU = {0.f, 0.f, 0.f, 0.f};
    f4 accV = {0.f, 0.f, 0.f, 0.f};

    #pragma unroll
    for (int jj = 0; jj < JIT; ++jj) {                   // fully unrolled: all
        const int cur = jj % 3;                          // buffer indices static
        const int q   = lane + 64 * jj;

        if (jj + 2 < JIT) {
            const int nx = (jj + 2) % 3;
            const int qn = q + 128;
            av[nx] = __builtin_nontemporal_load(&arow[qn]);
            lv[nx] = __builtin_nontemporal_load(&lrow[qn]);
            bv[nx] = brow[qn];
        }

        // (s,c) fp16 pairs for this quad, one b128 per d.
        const uint4 w0 = lsc[0 * QQ + q];
        const uint4 w1 = lsc[1 * QQ + q];
        const uint4 w2 = lsc[2 * QQ + q];
        const uint4 w3 = lsc[3 * QQ + q];
        const unsigned wq[4][4] = {
            {w0.x, w0.y, w0.z, w0.w},
            {w1.x, w1.y, w1.z, w1.w},
            {w2.x, w2.y, w2.z, w2.w},
            {w3.x, w3.y, w3.z, w3.w},
        };

        const f4 alr = lv[cur] + bv[cur];
        const f4 af  = av[cur];
        #pragma unroll
        for (int u = 0; u < 4; ++u) {
            float sa, ca;
            __sincosf(alr[u], &sa, &ca);
            const float wc = af[u] * ca;
            const float ws = af[u] * sa;
#ifdef USE_FDOT2
            // accU[d] += wc*s - ws*c ; accV[d] += ws*s + wc*c
            const h2 pw = __builtin_bit_cast(h2, __builtin_amdgcn_cvt_pkrtz(wc, -ws));
            const h2 pv = __builtin_bit_cast(h2, __builtin_amdgcn_cvt_pkrtz(ws,  wc));
            #pragma unroll
            for (int d = 0; d < 4; ++d) {
                const h2 pr = __builtin_bit_cast(h2, wq[d][u]);
                accU[d] = __builtin_amdgcn_fdot2(pw, pr, accU[d], false);
                accV[d] = __builtin_amdgcn_fdot2(pv, pr, accV[d], false);
            }
#else
            #pragma unroll
            for (int d = 0; d < 4; ++d) {
                const h2 pr = __builtin_bit_cast(h2, wq[d][u]);
                const float sj = (float)pr[0];
                const float cj = (float)pr[1];
                accU[d] += wc * sj - ws * cj;
                accV[d] += wc * cj + ws * sj;
            }
#endif
        }
    }

    // ---- wave-local shuffle reduction; no barrier needed ----
    #pragma unroll
    for (int off = 32; off >= 1; off >>= 1) {
        #pragma unroll
        for (int d = 0; d < 4; ++d) {
            accU[d] += __shfl_down(accU[d], off, 64);
            accV[d] += __shfl_down(accV[d], off, 64);
        }
    }

    if (lane == 0) {
        const f4* gam4 = (const f4*)gam;
        const f4* om4  = (const f4*)omega;
        const f4* kp4  = (const f4*)kappa;
        f4* out4       = (f4*)out;

        const size_t base = (size_t)b * NN + i;
        const f4 th = theta4[i];                         // theta4 already offset by b*NN
        const f4 gm = gam4[base];
        const f4 om = om4[i];
        const f4 kp = kp4[i];
        f4 o;
        #pragma unroll
        for (int d = 0; d < 4; ++d) {
            float si, ci;
            __sincosf(th[d], &si, &ci);                  // fp32 epilogue sincos, inline
            const float coup = (1.0f / (float)NN) * (ci * accU[d] - si * accV[d]);
            o[d] = th[d] + om[d] + kp[d] * (gm[d] - th[d]) + coup;
        }
        out4[base] = o;
    }
}

extern "C" void kernel_launch(void* const* d_in, const int* in_sizes, int n_in,
                              void* d_out, int out_size, void* d_ws, size_t ws_size,
                              hipStream_t stream) {
    const float* theta = (const float*)d_in[0];
    const float* gam   = (const float*)d_in[1];
    const float* aff   = (const float*)d_in[2];
    const float* alp   = (const float*)d_in[3];
    const float* omega = (const float*)d_in[4];
    const float* kappa = (const float*)d_in[5];
    const float* bias  = (const float*)d_in[6];
    float* out  = (float*)d_out;
    (void)d_ws; (void)ws_size;                           // workspace not used

    kuramoto_fused<<<BB * (NN / 4), BLOCK, 0, stream>>>(
        theta, gam, aff, alp, omega, kappa, bias, out);
}

// Round 5
// 165.711 us; speedup vs baseline: 1.0206x; 1.0043x over previous
//
#include <hip/hip_runtime.h>

#define BB 4
#define NN 2048
#define DD 4
#define QQ (NN / 4)          // 512 quads along j
#define BLOCK 512            // 8 waves/block, 8 rows/block
#define WPB 8                // waves per block
#define JIT (QQ / 64)        // 8 j-iterations per lane

typedef float f4 __attribute__((ext_vector_type(4)));
typedef _Float16 h2 __attribute__((ext_vector_type(2)));

#if __has_builtin(__builtin_amdgcn_fdot2) && __has_builtin(__builtin_amdgcn_cvt_pkrtz)
#define USE_FDOT2 1
#endif

static __device__ __forceinline__ unsigned pack_sc(float s, float c) {
#ifdef USE_FDOT2
    return __builtin_bit_cast(unsigned, __builtin_amdgcn_cvt_pkrtz(s, c));
#else
    h2 p; p[0] = (_Float16)s; p[1] = (_Float16)c;
    return __builtin_bit_cast(unsigned, p);
#endif
}

// ---------------- single fused kernel: 1024 blocks, 8 waves/block, one row per wave.
// 8 adjacent rows per block -> each of the 3 global streams covers a contiguous
// 64 KB panel (DRAM row locality); sincos table built once per block (1024 builds
// total, half of the 256-thread version). Depth-2 rotating prefetch; two tiles
// issued before the table build so HBM latency hides under the sincos phase.
__global__ __launch_bounds__(BLOCK, 4) void kuramoto_fused(
    const float* __restrict__ theta,
    const float* __restrict__ gam,
    const float* __restrict__ aff,
    const float* __restrict__ alp,
    const float* __restrict__ omega,
    const float* __restrict__ kappa,
    const float* __restrict__ bias,
    float* __restrict__ out)
{
    // XCD swizzle: batch-siblings x, x+8, x+16, x+24 share row-group g, differ in
    // batch b, and land on the same XCD (x%8) close in time -> bias-row L2 reuse.
    const int x   = blockIdx.x;                          // [0, 1024)
    const int low = x & 31;
    const int b   = low >> 3;
    const int g   = (x >> 5) * 8 + (low & 7);            // row-group [0, 256)
    const int i0  = g * 8;

    const int tid  = threadIdx.x;
    const int wave = tid >> 6;                           // [0, 8)
    const int lane = tid & 63;
    const int i    = i0 + wave;                          // this wave's row

    const f4* arow = (const f4*)(aff + (size_t)b * NN * NN) + (size_t)i * QQ;
    const f4* lrow = (const f4*)(alp + (size_t)b * NN * NN) + (size_t)i * QQ;
    const f4* brow = (const f4*)bias + (size_t)i * QQ;

    // ---- issue tiles 0 and 1 early: latency hides under the sincos table build ----
    f4 av[3], lv[3], bv[3];
    av[0] = __builtin_nontemporal_load(&arow[lane]);
    lv[0] = __builtin_nontemporal_load(&lrow[lane]);
    bv[0] = brow[lane];
    av[1] = __builtin_nontemporal_load(&arow[lane + 64]);
    lv[1] = __builtin_nontemporal_load(&lrow[lane + 64]);
    bv[1] = brow[lane + 64];

    // ---- build this batch's sincos table in LDS (32 KB), one quad per thread ----
    // entry (d, q) = 4 fp16 (s,c) pairs for j = 4q..4q+3; each 32-bit word is a
    // ready-made v_dot2_f32_f16 operand {sin(θj), cos(θj)}.
    __shared__ uint4 lsc[4 * QQ];
    const f4* theta4 = (const f4*)theta + (size_t)b * NN;
    {
        const int q = tid;                               // QQ == BLOCK
        float s[4][4], c[4][4];                          // [u][d]
        #pragma unroll
        for (int u = 0; u < 4; ++u) {
            const f4 th = theta4[4 * q + u];
            #pragma unroll
            for (int d = 0; d < 4; ++d) __sincosf(th[d], &s[u][d], &c[u][d]);
        }
        #pragma unroll
        for (int d = 0; d < 4; ++d) {
            uint4 w;
            w.x = pack_sc(s[0][d], c[0][d]);
            w.y = pack_sc(s[1][d], c[1][d]);
            w.z = pack_sc(s[2][d], c[2][d]);
            w.w = pack_sc(s[3][d], c[3][d]);
            lsc[d * QQ + q] = w;
        }
    }
    __syncthreads();

    f4 accU = {0.f, 0.f, 0.f, 0.f};
    f4 accV = {0.f, 0.f, 0.f, 0.f};

    #pragma unroll
    for (int jj = 0; jj < JIT; ++jj) {                   // fully unrolled: all
        const int cur = jj % 3;                          // buffer indices static
        const int q   = lane + 64 * jj;

        if (jj + 2 < JIT) {
            const int nx = (jj + 2) % 3;
            const int qn = q + 128;
            av[nx] = __builtin_nontemporal_load(&arow[qn]);
            lv[nx] = __builtin_nontemporal_load(&lrow[qn]);
            bv[nx] = brow[qn];
        }

        // (s,c) fp16 pairs for this quad, one b128 per d.
        const uint4 w0 = lsc[0 * QQ + q];
        const uint4 w1 = lsc[1 * QQ + q];
        const uint4 w2 = lsc[2 * QQ + q];
        const uint4 w3 = lsc[3 * QQ + q];
        const unsigned wq[4][4] = {
            {w0.x, w0.y, w0.z, w0.w},
            {w1.x, w1.y, w1.z, w1.w},
            {w2.x, w2.y, w2.z, w2.w},
            {w3.x, w3.y, w3.z, w3.w},
        };

        const f4 alr = lv[cur] + bv[cur];
        const f4 af  = av[cur];
        #pragma unroll
        for (int u = 0; u < 4; ++u) {
            float sa, ca;
            __sincosf(alr[u], &sa, &ca);
            const float wc = af[u] * ca;
            const float ws = af[u] * sa;
#ifdef USE_FDOT2
            // accU[d] += wc*s - ws*c ; accV[d] += ws*s + wc*c
            const h2 pw = __builtin_bit_cast(h2, __builtin_amdgcn_cvt_pkrtz(wc, -ws));
            const h2 pv = __builtin_bit_cast(h2, __builtin_amdgcn_cvt_pkrtz(ws,  wc));
            #pragma unroll
            for (int d = 0; d < 4; ++d) {
                const h2 pr = __builtin_bit_cast(h2, wq[d][u]);
                accU[d] = __builtin_amdgcn_fdot2(pw, pr, accU[d], false);
                accV[d] = __builtin_amdgcn_fdot2(pv, pr, accV[d], false);
            }
#else
            #pragma unroll
            for (int d = 0; d < 4; ++d) {
                const h2 pr = __builtin_bit_cast(h2, wq[d][u]);
                const float sj = (float)pr[0];
                const float cj = (float)pr[1];
                accU[d] += wc * sj - ws * cj;
                accV[d] += wc * cj + ws * sj;
            }
#endif
        }
    }

    // ---- wave-local shuffle reduction; no barrier needed ----
    #pragma unroll
    for (int off = 32; off >= 1; off >>= 1) {
        #pragma unroll
        for (int d = 0; d < 4; ++d) {
            accU[d] += __shfl_down(accU[d], off, 64);
            accV[d] += __shfl_down(accV[d], off, 64);
        }
    }

    if (lane == 0) {
        const f4* gam4 = (const f4*)gam;
        const f4* om4  = (const f4*)omega;
        const f4* kp4  = (const f4*)kappa;
        f4* out4       = (f4*)out;

        const size_t base = (size_t)b * NN + i;
        const f4 th = theta4[i];                         // theta4 already offset by b*NN
        const f4 gm = gam4[base];
        const f4 om = om4[i];
        const f4 kp = kp4[i];
        f4 o;
        #pragma unroll
        for (int d = 0; d < 4; ++d) {
            float si, ci;
            __sincosf(th[d], &si, &ci);                  // fp32 epilogue sincos, inline
            const float coup = (1.0f / (float)NN) * (ci * accU[d] - si * accV[d]);
            o[d] = th[d] + om[d] + kp[d] * (gm[d] - th[d]) + coup;
        }
        out4[base] = o;
    }
}

extern "C" void kernel_launch(void* const* d_in, const int* in_sizes, int n_in,
                              void* d_out, int out_size, void* d_ws, size_t ws_size,
                              hipStream_t stream) {
    const float* theta = (const float*)d_in[0];
    const float* gam   = (const float*)d_in[1];
    const float* aff   = (const float*)d_in[2];
    const float* alp   = (const float*)d_in[3];
    const float* omega = (const float*)d_in[4];
    const float* kappa = (const float*)d_in[5];
    const float* bias  = (const float*)d_in[6];
    float* out  = (float*)d_out;
    (void)d_ws; (void)ws_size;                           // workspace not used

    kuramoto_fused<<<BB * (NN / 8), BLOCK, 0, stream>>>(
        theta, gam, aff, alp, omega, kappa, bias, out);
}